// Round 2
// baseline (512.906 us; speedup 1.0000x reference)
//
#include <hip/hip_runtime.h>
#include <math.h>

#define NN 50000
#define NE 800000
#define C  128
#define GN 32   // nodes per GEMM block

// ---------- small helpers ----------
__global__ void k_transpose(const float* __restrict__ W, float* __restrict__ Wt) {
  int i = blockIdx.x * 256 + threadIdx.x;      // 16384 elements
  if (i < C * C) {
    int o = i >> 7, c = i & 127;
    Wt[c * C + o] = W[i];
  }
}

__global__ void k_hist(const int* __restrict__ dst, int* __restrict__ deg) {
  int e = blockIdx.x * 256 + threadIdx.x;
  if (e < NE) atomicAdd(&deg[dst[e]], 1);
}

// single-block exclusive scan over deg[0..NN) -> rowstart, cursor; rowstart[NN]=E
__global__ __launch_bounds__(1024) void k_scan(const int* __restrict__ deg,
                                               int* __restrict__ rowstart,
                                               int* __restrict__ cursor) {
  __shared__ int lds[1024];
  int t = threadIdx.x;
  int carry = 0;
  for (int base = 0; base < NN; base += 1024) {
    int i = base + t;
    int v = (i < NN) ? deg[i] : 0;
    lds[t] = v;
    __syncthreads();
    for (int off = 1; off < 1024; off <<= 1) {
      int u = (t >= off) ? lds[t - off] : 0;
      __syncthreads();
      lds[t] += u;
      __syncthreads();
    }
    int incl = lds[t];
    int total = lds[1023];
    if (i < NN) { rowstart[i] = carry + incl - v; cursor[i] = carry + incl - v; }
    carry += total;
    __syncthreads();
  }
  if (t == 0) rowstart[NN] = carry;
}

__global__ void k_fill(const int* __restrict__ src, const int* __restrict__ dst,
                       int* __restrict__ cursor, int* __restrict__ csr) {
  int e = blockIdx.x * 256 + threadIdx.x;
  if (e < NE) {
    int pos = atomicAdd(&cursor[dst[e]], 1);
    csr[pos] = src[e];
  }
}

// ---------- aggregation: per-node max over incoming edges, fused (1+eps)*x + agg ----------
__global__ __launch_bounds__(128) void k_agg_pre(const float* __restrict__ xin,
                       const int* __restrict__ rs, const int* __restrict__ csr,
                       const float* __restrict__ eps_p, float* __restrict__ pre) {
  int n = blockIdx.x;
  int t = threadIdx.x;
  int s0 = rs[n], s1 = rs[n + 1];
  float acc = -INFINITY;
  for (int j = s0; j < s1; ++j) {
    int s = csr[j];
    acc = fmaxf(acc, xin[(size_t)s * C + t]);
  }
  if (s1 == s0) acc = 0.0f;   // empty segment -> 0 (PyG fill semantics)
  float e1 = 1.0f + eps_p[0];
  pre[(size_t)n * C + t] = fmaf(e1, xin[(size_t)n * C + t], acc);
}

// ---------- GEMM: out[n][o] = sum_c A[n][c] * Wt[c][o] + bias[o] ----------
#define ACCK(K) { \
  float4 a = *(const float4*)(sA + (ng * 4 + (K)) * C + c); \
  acc[K][0] = fmaf(a.x, w0.x, acc[K][0]); acc[K][1] = fmaf(a.x, w0.y, acc[K][1]); \
  acc[K][2] = fmaf(a.x, w0.z, acc[K][2]); acc[K][3] = fmaf(a.x, w0.w, acc[K][3]); \
  acc[K][0] = fmaf(a.y, w1.x, acc[K][0]); acc[K][1] = fmaf(a.y, w1.y, acc[K][1]); \
  acc[K][2] = fmaf(a.y, w1.z, acc[K][2]); acc[K][3] = fmaf(a.y, w1.w, acc[K][3]); \
  acc[K][0] = fmaf(a.z, w2.x, acc[K][0]); acc[K][1] = fmaf(a.z, w2.y, acc[K][1]); \
  acc[K][2] = fmaf(a.z, w2.z, acc[K][2]); acc[K][3] = fmaf(a.z, w2.w, acc[K][3]); \
  acc[K][0] = fmaf(a.w, w3.x, acc[K][0]); acc[K][1] = fmaf(a.w, w3.y, acc[K][1]); \
  acc[K][2] = fmaf(a.w, w3.z, acc[K][2]); acc[K][3] = fmaf(a.w, w3.w, acc[K][3]); }

__global__ __launch_bounds__(256) void k_gemm(const float* __restrict__ A,
                       const float* __restrict__ Wt, const float* __restrict__ bias,
                       float* __restrict__ out) {
  __shared__ float sW[C * C];      // 64 KB, Wt layout [c][o]
  __shared__ float sA[GN * C];     // 16 KB, row-major [n][c]
  int t = threadIdx.x;
  int nbase = blockIdx.x * GN;

  const float4* Wt4 = (const float4*)Wt;
  float4* sW4 = (float4*)sW;
  #pragma unroll
  for (int it = 0; it < 16; ++it) sW4[it * 256 + t] = Wt4[it * 256 + t];

  float4* sA4 = (float4*)sA;
  #pragma unroll
  for (int it = 0; it < 4; ++it) {
    int idx = it * 256 + t;              // float4 index; 32 float4 per row
    int row = nbase + (idx >> 5);
    float4 v = make_float4(0.f, 0.f, 0.f, 0.f);
    if (row < NN) v = ((const float4*)A)[(size_t)row * (C / 4) + (idx & 31)];
    sA4[idx] = v;
  }
  __syncthreads();

  int on = t & 31;     // output quad: o = 4*on
  int ng = t >> 5;     // node group: nodes ng*4 .. ng*4+3
  float4 b4 = ((const float4*)bias)[on];
  float acc[4][4];
  #pragma unroll
  for (int k = 0; k < 4; ++k) {
    acc[k][0] = b4.x; acc[k][1] = b4.y; acc[k][2] = b4.z; acc[k][3] = b4.w;
  }

  for (int c = 0; c < C; c += 4) {
    float4 w0 = *(const float4*)(sW + (c + 0) * C + 4 * on);
    float4 w1 = *(const float4*)(sW + (c + 1) * C + 4 * on);
    float4 w2 = *(const float4*)(sW + (c + 2) * C + 4 * on);
    float4 w3 = *(const float4*)(sW + (c + 3) * C + 4 * on);
    ACCK(0) ACCK(1) ACCK(2) ACCK(3)
  }

  #pragma unroll
  for (int k = 0; k < 4; ++k) {
    int row = nbase + ng * 4 + k;
    if (row < NN) {
      float4 o4 = make_float4(acc[k][0], acc[k][1], acc[k][2], acc[k][3]);
      ((float4*)out)[(size_t)row * (C / 4) + on] = o4;
    }
  }
}

// ---------- global LayerNorm stats (sum, sumsq over all N*C) ----------
__global__ __launch_bounds__(256) void k_stats(const float* __restrict__ h,
                                               double* __restrict__ st) {
  const int NV = NN * C / 4;
  int stride = gridDim.x * blockDim.x;
  double s = 0.0, ss = 0.0;
  for (int i = blockIdx.x * blockDim.x + threadIdx.x; i < NV; i += stride) {
    float4 v = ((const float4*)h)[i];
    s  += (double)v.x + (double)v.y + (double)v.z + (double)v.w;
    ss += (double)v.x * v.x + (double)v.y * v.y + (double)v.z * v.z + (double)v.w * v.w;
  }
  // wave reduce
  for (int off = 32; off > 0; off >>= 1) {
    s  += __shfl_down(s, off, 64);
    ss += __shfl_down(ss, off, 64);
  }
  __shared__ double sd[4], ssd[4];
  int wid = threadIdx.x >> 6, lane = threadIdx.x & 63;
  if (lane == 0) { sd[wid] = s; ssd[wid] = ss; }
  __syncthreads();
  if (threadIdx.x == 0) {
    double ts = sd[0] + sd[1] + sd[2] + sd[3];
    double tss = ssd[0] + ssd[1] + ssd[2] + ssd[3];
    atomicAdd(&st[0], ts);
    atomicAdd(&st[1], tss);
  }
}

__global__ void k_final(const double* __restrict__ st, float* __restrict__ scal) {
  double M = (double)NN * C;
  double mean = st[0] / M;
  double var = st[1] / M - mean * mean;
  if (var < 0.0) var = 0.0;
  double stdv = sqrt(var);
  scal[0] = (float)mean;
  scal[1] = (float)(1.0 / (stdv + 1e-5));
}

// ---------- LN apply + PReLU ----------
__global__ __launch_bounds__(256) void k_act(const float* __restrict__ h,
                       const float* __restrict__ scal,
                       const float* __restrict__ lw, const float* __restrict__ lb,
                       const float* __restrict__ a_p, float* __restrict__ outb) {
  int i = blockIdx.x * 256 + threadIdx.x;   // float4 index, total NN*C/4
  if (i >= NN * C / 4) return;
  float mean = scal[0], inv = scal[1], a = a_p[0];
  float4 v = ((const float4*)h)[i];
  int c4 = i & 31;
  float4 w = ((const float4*)lw)[c4];
  float4 b = ((const float4*)lb)[c4];
  float r[4];
  r[0] = (v.x - mean) * inv * w.x + b.x;
  r[1] = (v.y - mean) * inv * w.y + b.y;
  r[2] = (v.z - mean) * inv * w.z + b.z;
  r[3] = (v.w - mean) * inv * w.w + b.w;
  #pragma unroll
  for (int k = 0; k < 4; ++k) r[k] = (r[k] >= 0.f) ? r[k] : a * r[k];
  ((float4*)outb)[i] = make_float4(r[0], r[1], r[2], r[3]);
}

extern "C" void kernel_launch(void* const* d_in, const int* in_sizes, int n_in,
                              void* d_out, int out_size, void* d_ws, size_t ws_size,
                              hipStream_t stream) {
  const float* x    = (const float*)d_in[0];
  const int*   ei   = (const int*)d_in[1];
  const float* eps1 = (const float*)d_in[2];
  const float* W1   = (const float*)d_in[3];
  const float* b1   = (const float*)d_in[4];
  const float* lnw  = (const float*)d_in[5];
  const float* lnb  = (const float*)d_in[6];
  const float* pa   = (const float*)d_in[7];
  const float* eps2 = (const float*)d_in[8];
  const float* W2   = (const float*)d_in[9];
  const float* b2   = (const float*)d_in[10];
  float* out = (float*)d_out;
  const int* srcI = ei;         // edge_index[0]
  const int* dstI = ei + NE;    // edge_index[1]

  char* w = (char*)d_ws;
  float*  A      = (float*)(w);                  // 25,600,000 B
  float*  B      = (float*)(w + 25600000);       // 25,600,000 B
  float*  Wt1    = (float*)(w + 51200000);       // 65,536 B
  float*  Wt2    = (float*)(w + 51265536);       // 65,536 B
  int*    deg    = (int*)(w + 51331072);         // 200,000 B
  int*    rowst  = (int*)(w + 51531072);         // 200,064 B (N+1 ints)
  int*    cursor = (int*)(w + 51731136);         // 200,000 B
  int*    csr    = (int*)(w + 51931136);         // 3,200,000 B
  double* st     = (double*)(w + 55131136);      // 16 B
  float*  scal   = (float*)(w + 55131152);       // 8 B

  hipMemsetAsync(deg, 0, NN * sizeof(int), stream);
  hipMemsetAsync(st, 0, 2 * sizeof(double), stream);

  k_transpose<<<64, 256, 0, stream>>>(W1, Wt1);
  k_transpose<<<64, 256, 0, stream>>>(W2, Wt2);
  k_hist<<<(NE + 255) / 256, 256, 0, stream>>>(dstI, deg);
  k_scan<<<1, 1024, 0, stream>>>(deg, rowst, cursor);
  k_fill<<<(NE + 255) / 256, 256, 0, stream>>>(srcI, dstI, cursor, csr);

  // layer 1
  k_agg_pre<<<NN, 128, 0, stream>>>(x, rowst, csr, eps1, A);
  k_gemm<<<(NN + GN - 1) / GN, 256, 0, stream>>>(A, Wt1, b1, B);

  // graph layernorm + prelu
  k_stats<<<1024, 256, 0, stream>>>(B, st);
  k_final<<<1, 1, 0, stream>>>(st, scal);
  k_act<<<(NN * C / 4 + 255) / 256, 256, 0, stream>>>(B, scal, lnw, lnb, pa, A);

  // layer 2
  k_agg_pre<<<NN, 128, 0, stream>>>(A, rowst, csr, eps2, B);
  k_gemm<<<(NN + GN - 1) / GN, 256, 0, stream>>>(B, Wt2, b2, out);
}

// Round 3
// 429.138 us; speedup vs baseline: 1.1952x; 1.1952x over previous
//
#include <hip/hip_runtime.h>
#include <math.h>

#define NN 50000
#define NE 800000
#define C  128
#define GN 32          // nodes per GEMM block
#define SCAN_ELEM 1024 // elements per scan block
#define NBLK_SCAN ((NN + SCAN_ELEM - 1) / SCAN_ELEM)   // 49

// ---------- small helpers ----------
__global__ void k_transpose(const float* __restrict__ W, float* __restrict__ Wt) {
  int i = blockIdx.x * 256 + threadIdx.x;      // 16384 elements
  if (i < C * C) {
    int o = i >> 7, c = i & 127;
    Wt[c * C + o] = W[i];
  }
}

__global__ void k_hist(const int* __restrict__ dst, int* __restrict__ deg) {
  int e = blockIdx.x * 256 + threadIdx.x;
  if (e < NE) atomicAdd(&deg[dst[e]], 1);
}

// ---------- device-wide exclusive scan, 3 phases ----------
__global__ __launch_bounds__(256) void k_scan_p1(const int* __restrict__ deg,
                                                 int* __restrict__ partial,
                                                 int* __restrict__ prescan) {
  int t = threadIdx.x;
  int base = blockIdx.x * SCAN_ELEM;
  int idx = base + t * 4;
  int4 v = make_int4(0, 0, 0, 0);
  if (idx + 3 < NN) {
    v = *(const int4*)(deg + idx);
  } else {
    if (idx + 0 < NN) v.x = deg[idx + 0];
    if (idx + 1 < NN) v.y = deg[idx + 1];
    if (idx + 2 < NN) v.z = deg[idx + 2];
    if (idx + 3 < NN) v.w = deg[idx + 3];
  }
  int s0 = v.x, s1 = s0 + v.y, s2 = s1 + v.z, s3 = s2 + v.w;  // thread-local inclusive
  int tsum = s3;
  int lane = t & 63;
  int incl = tsum;
  #pragma unroll
  for (int off = 1; off < 64; off <<= 1) {
    int u = __shfl_up(incl, off, 64);
    if (lane >= off) incl += u;
  }
  __shared__ int wsum[4];
  int wid = t >> 6;
  if (lane == 63) wsum[wid] = incl;
  __syncthreads();
  int woff = 0;
  for (int wI = 0; wI < wid; ++wI) woff += wsum[wI];
  int texcl = woff + incl - tsum;  // exclusive prefix of this thread's first element
  if (idx + 0 < NN) prescan[idx + 0] = texcl;
  if (idx + 1 < NN) prescan[idx + 1] = texcl + s0;
  if (idx + 2 < NN) prescan[idx + 2] = texcl + s1;
  if (idx + 3 < NN) prescan[idx + 3] = texcl + s2;
  if (t == 255) partial[blockIdx.x] = woff + incl;  // block total
}

__global__ __launch_bounds__(64) void k_scan_p2(const int* __restrict__ partial,
                                                int* __restrict__ blkoff) {
  int t = threadIdx.x;  // 64 threads, NBLK_SCAN=49 <= 64
  int v = (t < NBLK_SCAN) ? partial[t] : 0;
  int incl = v;
  #pragma unroll
  for (int off = 1; off < 64; off <<= 1) {
    int u = __shfl_up(incl, off, 64);
    if (t >= off) incl += u;
  }
  if (t < NBLK_SCAN) blkoff[t] = incl - v;  // exclusive
}

__global__ __launch_bounds__(256) void k_scan_p3(const int* __restrict__ prescan,
                                                 const int* __restrict__ blkoff,
                                                 int* __restrict__ rowstart,
                                                 int* __restrict__ cursor) {
  int i = blockIdx.x * 256 + threadIdx.x;
  if (i < NN) {
    int v = prescan[i] + blkoff[i >> 10];
    rowstart[i] = v;
    cursor[i] = v;
  }
  if (i == 0) rowstart[NN] = NE;  // every edge lands in some segment
}

__global__ void k_fill(const int* __restrict__ src, const int* __restrict__ dst,
                       int* __restrict__ cursor, int* __restrict__ csr) {
  int e = blockIdx.x * 256 + threadIdx.x;
  if (e < NE) {
    int pos = atomicAdd(&cursor[dst[e]], 1);
    csr[pos] = src[e];
  }
}

// ---------- aggregation: per-node max over incoming edges, fused (1+eps)*x + agg ----------
__global__ __launch_bounds__(128) void k_agg_pre(const float* __restrict__ xin,
                       const int* __restrict__ rs, const int* __restrict__ csr,
                       const float* __restrict__ eps_p, float* __restrict__ pre) {
  int n = blockIdx.x;
  int t = threadIdx.x;
  int s0 = rs[n], s1 = rs[n + 1];
  float acc = -INFINITY;
  for (int j = s0; j < s1; ++j) {
    int s = csr[j];
    acc = fmaxf(acc, xin[(size_t)s * C + t]);
  }
  if (s1 == s0) acc = 0.0f;   // empty segment -> 0 (PyG fill semantics)
  float e1 = 1.0f + eps_p[0];
  pre[(size_t)n * C + t] = fmaf(e1, xin[(size_t)n * C + t], acc);
}

// ---------- GEMM: out[n][o] = sum_c A[n][c] * Wt[c][o] + bias[o] ----------
#define ACCK(K) { \
  float4 a = *(const float4*)(sA + (ng * 4 + (K)) * C + c); \
  acc[K][0] = fmaf(a.x, w0.x, acc[K][0]); acc[K][1] = fmaf(a.x, w0.y, acc[K][1]); \
  acc[K][2] = fmaf(a.x, w0.z, acc[K][2]); acc[K][3] = fmaf(a.x, w0.w, acc[K][3]); \
  acc[K][0] = fmaf(a.y, w1.x, acc[K][0]); acc[K][1] = fmaf(a.y, w1.y, acc[K][1]); \
  acc[K][2] = fmaf(a.y, w1.z, acc[K][2]); acc[K][3] = fmaf(a.y, w1.w, acc[K][3]); \
  acc[K][0] = fmaf(a.z, w2.x, acc[K][0]); acc[K][1] = fmaf(a.z, w2.y, acc[K][1]); \
  acc[K][2] = fmaf(a.z, w2.z, acc[K][2]); acc[K][3] = fmaf(a.z, w2.w, acc[K][3]); \
  acc[K][0] = fmaf(a.w, w3.x, acc[K][0]); acc[K][1] = fmaf(a.w, w3.y, acc[K][1]); \
  acc[K][2] = fmaf(a.w, w3.z, acc[K][2]); acc[K][3] = fmaf(a.w, w3.w, acc[K][3]); }

__global__ __launch_bounds__(256) void k_gemm(const float* __restrict__ A,
                       const float* __restrict__ Wt, const float* __restrict__ bias,
                       float* __restrict__ out) {
  __shared__ float sW[C * C];      // 64 KB, Wt layout [c][o]
  __shared__ float sA[GN * C];     // 16 KB, row-major [n][c]
  int t = threadIdx.x;
  int nbase = blockIdx.x * GN;

  const float4* Wt4 = (const float4*)Wt;
  float4* sW4 = (float4*)sW;
  #pragma unroll
  for (int it = 0; it < 16; ++it) sW4[it * 256 + t] = Wt4[it * 256 + t];

  float4* sA4 = (float4*)sA;
  #pragma unroll
  for (int it = 0; it < 4; ++it) {
    int idx = it * 256 + t;              // float4 index; 32 float4 per row
    int row = nbase + (idx >> 5);
    float4 v = make_float4(0.f, 0.f, 0.f, 0.f);
    if (row < NN) v = ((const float4*)A)[(size_t)row * (C / 4) + (idx & 31)];
    sA4[idx] = v;
  }
  __syncthreads();

  int on = t & 31;     // output quad: o = 4*on
  int ng = t >> 5;     // node group: nodes ng*4 .. ng*4+3
  float4 b4 = ((const float4*)bias)[on];
  float acc[4][4];
  #pragma unroll
  for (int k = 0; k < 4; ++k) {
    acc[k][0] = b4.x; acc[k][1] = b4.y; acc[k][2] = b4.z; acc[k][3] = b4.w;
  }

  for (int c = 0; c < C; c += 4) {
    float4 w0 = *(const float4*)(sW + (c + 0) * C + 4 * on);
    float4 w1 = *(const float4*)(sW + (c + 1) * C + 4 * on);
    float4 w2 = *(const float4*)(sW + (c + 2) * C + 4 * on);
    float4 w3 = *(const float4*)(sW + (c + 3) * C + 4 * on);
    ACCK(0) ACCK(1) ACCK(2) ACCK(3)
  }

  #pragma unroll
  for (int k = 0; k < 4; ++k) {
    int row = nbase + ng * 4 + k;
    if (row < NN) {
      float4 o4 = make_float4(acc[k][0], acc[k][1], acc[k][2], acc[k][3]);
      ((float4*)out)[(size_t)row * (C / 4) + on] = o4;
    }
  }
}

// ---------- global LayerNorm stats (sum, sumsq over all N*C) ----------
__global__ __launch_bounds__(256) void k_stats(const float* __restrict__ h,
                                               double* __restrict__ st) {
  const int NV = NN * C / 4;
  int stride = gridDim.x * blockDim.x;
  double s = 0.0, ss = 0.0;
  for (int i = blockIdx.x * blockDim.x + threadIdx.x; i < NV; i += stride) {
    float4 v = ((const float4*)h)[i];
    s  += (double)v.x + (double)v.y + (double)v.z + (double)v.w;
    ss += (double)v.x * v.x + (double)v.y * v.y + (double)v.z * v.z + (double)v.w * v.w;
  }
  for (int off = 32; off > 0; off >>= 1) {
    s  += __shfl_down(s, off, 64);
    ss += __shfl_down(ss, off, 64);
  }
  __shared__ double sd[4], ssd[4];
  int wid = threadIdx.x >> 6, lane = threadIdx.x & 63;
  if (lane == 0) { sd[wid] = s; ssd[wid] = ss; }
  __syncthreads();
  if (threadIdx.x == 0) {
    double ts = sd[0] + sd[1] + sd[2] + sd[3];
    double tss = ssd[0] + ssd[1] + ssd[2] + ssd[3];
    atomicAdd(&st[0], ts);
    atomicAdd(&st[1], tss);
  }
}

__global__ void k_final(const double* __restrict__ st, float* __restrict__ scal) {
  double M = (double)NN * C;
  double mean = st[0] / M;
  double var = st[1] / M - mean * mean;
  if (var < 0.0) var = 0.0;
  double stdv = sqrt(var);
  scal[0] = (float)mean;
  scal[1] = (float)(1.0 / (stdv + 1e-5));
}

// ---------- LN apply + PReLU ----------
__global__ __launch_bounds__(256) void k_act(const float* __restrict__ h,
                       const float* __restrict__ scal,
                       const float* __restrict__ lw, const float* __restrict__ lb,
                       const float* __restrict__ a_p, float* __restrict__ outb) {
  int i = blockIdx.x * 256 + threadIdx.x;   // float4 index, total NN*C/4
  if (i >= NN * C / 4) return;
  float mean = scal[0], inv = scal[1], a = a_p[0];
  float4 v = ((const float4*)h)[i];
  int c4 = i & 31;
  float4 w = ((const float4*)lw)[c4];
  float4 b = ((const float4*)lb)[c4];
  float r[4];
  r[0] = (v.x - mean) * inv * w.x + b.x;
  r[1] = (v.y - mean) * inv * w.y + b.y;
  r[2] = (v.z - mean) * inv * w.z + b.z;
  r[3] = (v.w - mean) * inv * w.w + b.w;
  #pragma unroll
  for (int k = 0; k < 4; ++k) r[k] = (r[k] >= 0.f) ? r[k] : a * r[k];
  ((float4*)outb)[i] = make_float4(r[0], r[1], r[2], r[3]);
}

extern "C" void kernel_launch(void* const* d_in, const int* in_sizes, int n_in,
                              void* d_out, int out_size, void* d_ws, size_t ws_size,
                              hipStream_t stream) {
  const float* x    = (const float*)d_in[0];
  const int*   ei   = (const int*)d_in[1];
  const float* eps1 = (const float*)d_in[2];
  const float* W1   = (const float*)d_in[3];
  const float* b1   = (const float*)d_in[4];
  const float* lnw  = (const float*)d_in[5];
  const float* lnb  = (const float*)d_in[6];
  const float* pa   = (const float*)d_in[7];
  const float* eps2 = (const float*)d_in[8];
  const float* W2   = (const float*)d_in[9];
  const float* b2   = (const float*)d_in[10];
  float* out = (float*)d_out;
  const int* srcI = ei;         // edge_index[0]
  const int* dstI = ei + NE;    // edge_index[1]

  char* w = (char*)d_ws;
  float*  A      = (float*)(w);                  // 25,600,000 B
  float*  B      = (float*)(w + 25600000);       // 25,600,000 B
  float*  Wt1    = (float*)(w + 51200000);       // 65,536 B
  float*  Wt2    = (float*)(w + 51265536);       // 65,536 B
  int*    deg    = (int*)(w + 51331072);         // 200,000 B
  int*    rowst  = (int*)(w + 51531072);         // 200,064 B (N+1 ints)
  int*    cursor = (int*)(w + 51731136);         // 200,000 B
  int*    csr    = (int*)(w + 51931136);         // 3,200,000 B
  double* st     = (double*)(w + 55131136);      // 16 B
  float*  scal   = (float*)(w + 55131152);       // 8 B
  int*    presc  = (int*)(w + 55131200);         // 200,000 B
  int*    spart  = (int*)(w + 55331200);         // 256 B (49 block totals)
  int*    sboff  = (int*)(w + 55331456);         // 256 B

  hipMemsetAsync(deg, 0, NN * sizeof(int), stream);
  hipMemsetAsync(st, 0, 2 * sizeof(double), stream);

  k_transpose<<<64, 256, 0, stream>>>(W1, Wt1);
  k_transpose<<<64, 256, 0, stream>>>(W2, Wt2);
  k_hist<<<(NE + 255) / 256, 256, 0, stream>>>(dstI, deg);
  k_scan_p1<<<NBLK_SCAN, 256, 0, stream>>>(deg, spart, presc);
  k_scan_p2<<<1, 64, 0, stream>>>(spart, sboff);
  k_scan_p3<<<(NN + 255) / 256, 256, 0, stream>>>(presc, sboff, rowst, cursor);
  k_fill<<<(NE + 255) / 256, 256, 0, stream>>>(srcI, dstI, cursor, csr);

  // layer 1
  k_agg_pre<<<NN, 128, 0, stream>>>(x, rowst, csr, eps1, A);
  k_gemm<<<(NN + GN - 1) / GN, 256, 0, stream>>>(A, Wt1, b1, B);

  // graph layernorm + prelu
  k_stats<<<1024, 256, 0, stream>>>(B, st);
  k_final<<<1, 1, 0, stream>>>(st, scal);
  k_act<<<(NN * C / 4 + 255) / 256, 256, 0, stream>>>(B, scal, lnw, lnb, pa, A);

  // layer 2
  k_agg_pre<<<NN, 128, 0, stream>>>(A, rowst, csr, eps2, B);
  k_gemm<<<(NN + GN - 1) / GN, 256, 0, stream>>>(B, Wt2, b2, out);
}

// Round 4
// 377.360 us; speedup vs baseline: 1.3592x; 1.1372x over previous
//
#include <hip/hip_runtime.h>
#include <hip/hip_fp16.h>
#include <math.h>

#define NN 50000
#define NE 800000
#define C  128
#define GN 32          // nodes per GEMM block
#define SCAN_ELEM 1024 // elements per scan block
#define NBLK_SCAN ((NN + SCAN_ELEM - 1) / SCAN_ELEM)   // 49

// ---------- small helpers ----------
__global__ void k_transpose(const float* __restrict__ W, float* __restrict__ Wt) {
  int i = blockIdx.x * 256 + threadIdx.x;      // 16384 elements
  if (i < C * C) {
    int o = i >> 7, c = i & 127;
    Wt[c * C + o] = W[i];
  }
}

__global__ void k_hist(const int* __restrict__ dst, int* __restrict__ deg) {
  int e = blockIdx.x * 256 + threadIdx.x;
  if (e < NE) atomicAdd(&deg[dst[e]], 1);
}

// ---------- device-wide exclusive scan, 3 phases ----------
__global__ __launch_bounds__(256) void k_scan_p1(const int* __restrict__ deg,
                                                 int* __restrict__ partial,
                                                 int* __restrict__ prescan) {
  int t = threadIdx.x;
  int base = blockIdx.x * SCAN_ELEM;
  int idx = base + t * 4;
  int4 v = make_int4(0, 0, 0, 0);
  if (idx + 3 < NN) {
    v = *(const int4*)(deg + idx);
  } else {
    if (idx + 0 < NN) v.x = deg[idx + 0];
    if (idx + 1 < NN) v.y = deg[idx + 1];
    if (idx + 2 < NN) v.z = deg[idx + 2];
    if (idx + 3 < NN) v.w = deg[idx + 3];
  }
  int s0 = v.x, s1 = s0 + v.y, s2 = s1 + v.z, s3 = s2 + v.w;  // thread-local inclusive
  int tsum = s3;
  int lane = t & 63;
  int incl = tsum;
  #pragma unroll
  for (int off = 1; off < 64; off <<= 1) {
    int u = __shfl_up(incl, off, 64);
    if (lane >= off) incl += u;
  }
  __shared__ int wsum[4];
  int wid = t >> 6;
  if (lane == 63) wsum[wid] = incl;
  __syncthreads();
  int woff = 0;
  for (int wI = 0; wI < wid; ++wI) woff += wsum[wI];
  int texcl = woff + incl - tsum;  // exclusive prefix of this thread's first element
  if (idx + 0 < NN) prescan[idx + 0] = texcl;
  if (idx + 1 < NN) prescan[idx + 1] = texcl + s0;
  if (idx + 2 < NN) prescan[idx + 2] = texcl + s1;
  if (idx + 3 < NN) prescan[idx + 3] = texcl + s2;
  if (t == 255) partial[blockIdx.x] = woff + incl;  // block total
}

__global__ __launch_bounds__(64) void k_scan_p2(const int* __restrict__ partial,
                                                int* __restrict__ blkoff) {
  int t = threadIdx.x;  // 64 threads, NBLK_SCAN=49 <= 64
  int v = (t < NBLK_SCAN) ? partial[t] : 0;
  int incl = v;
  #pragma unroll
  for (int off = 1; off < 64; off <<= 1) {
    int u = __shfl_up(incl, off, 64);
    if (t >= off) incl += u;
  }
  if (t < NBLK_SCAN) blkoff[t] = incl - v;  // exclusive
}

__global__ __launch_bounds__(256) void k_scan_p3(const int* __restrict__ prescan,
                                                 const int* __restrict__ blkoff,
                                                 int* __restrict__ rowstart,
                                                 int* __restrict__ cursor) {
  int i = blockIdx.x * 256 + threadIdx.x;
  if (i < NN) {
    int v = prescan[i] + blkoff[i >> 10];
    rowstart[i] = v;
    cursor[i] = v;
  }
  if (i == 0) rowstart[NN] = NE;  // every edge lands in some segment
}

__global__ void k_fill(const int* __restrict__ src, const int* __restrict__ dst,
                       int* __restrict__ cursor, int* __restrict__ csr) {
  int e = blockIdx.x * 256 + threadIdx.x;
  if (e < NE) {
    int pos = atomicAdd(&cursor[dst[e]], 1);
    csr[pos] = src[e];
  }
}

// ---------- fp32 -> fp16 row copy ----------
__global__ __launch_bounds__(256) void k_tohalf(const float* __restrict__ in,
                                                __half2* __restrict__ o) {
  int i = blockIdx.x * 256 + threadIdx.x;   // float4 index
  if (i < NN * C / 4) {
    float4 v = ((const float4*)in)[i];
    o[2 * i]     = __floats2half2_rn(v.x, v.y);
    o[2 * i + 1] = __floats2half2_rn(v.z, v.w);
  }
}

// ---------- aggregation: one wave per node, fp16 gather, fused (1+eps)*x + agg ----------
// max over fp16 values == fp16(max over fp32 values): rounding is monotone.
__global__ __launch_bounds__(256) void k_agg_h(const __half2* __restrict__ xh2,
                       const float* __restrict__ xf,
                       const int* __restrict__ rs, const int* __restrict__ csr,
                       const float* __restrict__ eps_p, float* __restrict__ pre) {
  int wid = threadIdx.x >> 6;
  int lane = threadIdx.x & 63;
  int n = blockIdx.x * 4 + wid;
  if (n >= NN) return;
  int s0 = rs[n], s1 = rs[n + 1];
  float a0 = -INFINITY, a1 = -INFINITY;
  float b0 = -INFINITY, b1 = -INFINITY;
  float c0 = -INFINITY, c1 = -INFINITY;
  float d0 = -INFINITY, d1 = -INFINITY;
  int j = s0;
  for (; j + 3 < s1; j += 4) {
    int e0 = csr[j], e1_ = csr[j + 1], e2 = csr[j + 2], e3 = csr[j + 3];
    __half2 v0 = xh2[(size_t)e0 * 64 + lane];
    __half2 v1 = xh2[(size_t)e1_ * 64 + lane];
    __half2 v2 = xh2[(size_t)e2 * 64 + lane];
    __half2 v3 = xh2[(size_t)e3 * 64 + lane];
    a0 = fmaxf(a0, __low2float(v0)); a1 = fmaxf(a1, __high2float(v0));
    b0 = fmaxf(b0, __low2float(v1)); b1 = fmaxf(b1, __high2float(v1));
    c0 = fmaxf(c0, __low2float(v2)); c1 = fmaxf(c1, __high2float(v2));
    d0 = fmaxf(d0, __low2float(v3)); d1 = fmaxf(d1, __high2float(v3));
  }
  for (; j < s1; ++j) {
    int e0 = csr[j];
    __half2 v0 = xh2[(size_t)e0 * 64 + lane];
    a0 = fmaxf(a0, __low2float(v0)); a1 = fmaxf(a1, __high2float(v0));
  }
  float m0 = fmaxf(fmaxf(a0, b0), fmaxf(c0, d0));
  float m1 = fmaxf(fmaxf(a1, b1), fmaxf(c1, d1));
  if (s1 == s0) { m0 = 0.f; m1 = 0.f; }   // empty segment -> 0 (PyG fill)
  float e1v = 1.0f + eps_p[0];
  float2 xs = ((const float2*)xf)[(size_t)n * 64 + lane];
  float2 o;
  o.x = fmaf(e1v, xs.x, m0);
  o.y = fmaf(e1v, xs.y, m1);
  ((float2*)pre)[(size_t)n * 64 + lane] = o;
}

// ---------- GEMM: out[n][o] = sum_c A[n][c] * Wt[c][o] + bias[o] ----------
#define ACCK(K) { \
  float4 a = *(const float4*)(sA + (ng * 4 + (K)) * C + c); \
  acc[K][0] = fmaf(a.x, w0.x, acc[K][0]); acc[K][1] = fmaf(a.x, w0.y, acc[K][1]); \
  acc[K][2] = fmaf(a.x, w0.z, acc[K][2]); acc[K][3] = fmaf(a.x, w0.w, acc[K][3]); \
  acc[K][0] = fmaf(a.y, w1.x, acc[K][0]); acc[K][1] = fmaf(a.y, w1.y, acc[K][1]); \
  acc[K][2] = fmaf(a.y, w1.z, acc[K][2]); acc[K][3] = fmaf(a.y, w1.w, acc[K][3]); \
  acc[K][0] = fmaf(a.z, w2.x, acc[K][0]); acc[K][1] = fmaf(a.z, w2.y, acc[K][1]); \
  acc[K][2] = fmaf(a.z, w2.z, acc[K][2]); acc[K][3] = fmaf(a.z, w2.w, acc[K][3]); \
  acc[K][0] = fmaf(a.w, w3.x, acc[K][0]); acc[K][1] = fmaf(a.w, w3.y, acc[K][1]); \
  acc[K][2] = fmaf(a.w, w3.z, acc[K][2]); acc[K][3] = fmaf(a.w, w3.w, acc[K][3]); }

__global__ __launch_bounds__(256) void k_gemm(const float* __restrict__ A,
                       const float* __restrict__ Wt, const float* __restrict__ bias,
                       float* __restrict__ out) {
  __shared__ float sW[C * C];      // 64 KB, Wt layout [c][o]
  __shared__ float sA[GN * C];     // 16 KB, row-major [n][c]
  int t = threadIdx.x;
  int nbase = blockIdx.x * GN;

  const float4* Wt4 = (const float4*)Wt;
  float4* sW4 = (float4*)sW;
  #pragma unroll
  for (int it = 0; it < 16; ++it) sW4[it * 256 + t] = Wt4[it * 256 + t];

  float4* sA4 = (float4*)sA;
  #pragma unroll
  for (int it = 0; it < 4; ++it) {
    int idx = it * 256 + t;              // float4 index; 32 float4 per row
    int row = nbase + (idx >> 5);
    float4 v = make_float4(0.f, 0.f, 0.f, 0.f);
    if (row < NN) v = ((const float4*)A)[(size_t)row * (C / 4) + (idx & 31)];
    sA4[idx] = v;
  }
  __syncthreads();

  int on = t & 31;     // output quad: o = 4*on
  int ng = t >> 5;     // node group: nodes ng*4 .. ng*4+3
  float4 b4 = ((const float4*)bias)[on];
  float acc[4][4];
  #pragma unroll
  for (int k = 0; k < 4; ++k) {
    acc[k][0] = b4.x; acc[k][1] = b4.y; acc[k][2] = b4.z; acc[k][3] = b4.w;
  }

  for (int c = 0; c < C; c += 4) {
    float4 w0 = *(const float4*)(sW + (c + 0) * C + 4 * on);
    float4 w1 = *(const float4*)(sW + (c + 1) * C + 4 * on);
    float4 w2 = *(const float4*)(sW + (c + 2) * C + 4 * on);
    float4 w3 = *(const float4*)(sW + (c + 3) * C + 4 * on);
    ACCK(0) ACCK(1) ACCK(2) ACCK(3)
  }

  #pragma unroll
  for (int k = 0; k < 4; ++k) {
    int row = nbase + ng * 4 + k;
    if (row < NN) {
      float4 o4 = make_float4(acc[k][0], acc[k][1], acc[k][2], acc[k][3]);
      ((float4*)out)[(size_t)row * (C / 4) + on] = o4;
    }
  }
}

// ---------- global LayerNorm stats (sum, sumsq over all N*C) ----------
__global__ __launch_bounds__(256) void k_stats(const float* __restrict__ h,
                                               double* __restrict__ st) {
  const int NV = NN * C / 4;
  int stride = gridDim.x * blockDim.x;
  double s = 0.0, ss = 0.0;
  for (int i = blockIdx.x * blockDim.x + threadIdx.x; i < NV; i += stride) {
    float4 v = ((const float4*)h)[i];
    s  += (double)v.x + (double)v.y + (double)v.z + (double)v.w;
    ss += (double)v.x * v.x + (double)v.y * v.y + (double)v.z * v.z + (double)v.w * v.w;
  }
  for (int off = 32; off > 0; off >>= 1) {
    s  += __shfl_down(s, off, 64);
    ss += __shfl_down(ss, off, 64);
  }
  __shared__ double sd[4], ssd[4];
  int wid = threadIdx.x >> 6, lane = threadIdx.x & 63;
  if (lane == 0) { sd[wid] = s; ssd[wid] = ss; }
  __syncthreads();
  if (threadIdx.x == 0) {
    double ts = sd[0] + sd[1] + sd[2] + sd[3];
    double tss = ssd[0] + ssd[1] + ssd[2] + ssd[3];
    atomicAdd(&st[0], ts);
    atomicAdd(&st[1], tss);
  }
}

__global__ void k_final(const double* __restrict__ st, float* __restrict__ scal) {
  double M = (double)NN * C;
  double mean = st[0] / M;
  double var = st[1] / M - mean * mean;
  if (var < 0.0) var = 0.0;
  double stdv = sqrt(var);
  scal[0] = (float)mean;
  scal[1] = (float)(1.0 / (stdv + 1e-5));
}

// ---------- LN apply + PReLU; writes fp32 + fp16 copies ----------
__global__ __launch_bounds__(256) void k_act(const float* __restrict__ h,
                       const float* __restrict__ scal,
                       const float* __restrict__ lw, const float* __restrict__ lb,
                       const float* __restrict__ a_p, float* __restrict__ outb,
                       __half2* __restrict__ outh) {
  int i = blockIdx.x * 256 + threadIdx.x;   // float4 index, total NN*C/4
  if (i >= NN * C / 4) return;
  float mean = scal[0], inv = scal[1], a = a_p[0];
  float4 v = ((const float4*)h)[i];
  int c4 = i & 31;
  float4 w = ((const float4*)lw)[c4];
  float4 b = ((const float4*)lb)[c4];
  float r[4];
  r[0] = (v.x - mean) * inv * w.x + b.x;
  r[1] = (v.y - mean) * inv * w.y + b.y;
  r[2] = (v.z - mean) * inv * w.z + b.z;
  r[3] = (v.w - mean) * inv * w.w + b.w;
  #pragma unroll
  for (int k = 0; k < 4; ++k) r[k] = (r[k] >= 0.f) ? r[k] : a * r[k];
  ((float4*)outb)[i] = make_float4(r[0], r[1], r[2], r[3]);
  outh[2 * i]     = __floats2half2_rn(r[0], r[1]);
  outh[2 * i + 1] = __floats2half2_rn(r[2], r[3]);
}

extern "C" void kernel_launch(void* const* d_in, const int* in_sizes, int n_in,
                              void* d_out, int out_size, void* d_ws, size_t ws_size,
                              hipStream_t stream) {
  const float* x    = (const float*)d_in[0];
  const int*   ei   = (const int*)d_in[1];
  const float* eps1 = (const float*)d_in[2];
  const float* W1   = (const float*)d_in[3];
  const float* b1   = (const float*)d_in[4];
  const float* lnw  = (const float*)d_in[5];
  const float* lnb  = (const float*)d_in[6];
  const float* pa   = (const float*)d_in[7];
  const float* eps2 = (const float*)d_in[8];
  const float* W2   = (const float*)d_in[9];
  const float* b2   = (const float*)d_in[10];
  float* out = (float*)d_out;
  const int* srcI = ei;         // edge_index[0]
  const int* dstI = ei + NE;    // edge_index[1]

  char* w = (char*)d_ws;
  float*   A      = (float*)(w);                  // 25,600,000 B
  float*   B      = (float*)(w + 25600000);       // 25,600,000 B
  float*   Wt1    = (float*)(w + 51200000);       // 65,536 B
  float*   Wt2    = (float*)(w + 51265536);       // 65,536 B
  int*     deg    = (int*)(w + 51331072);         // 200,000 B
  int*     rowst  = (int*)(w + 51531072);         // 200,064 B (N+1 ints)
  int*     cursor = (int*)(w + 51731136);         // 200,000 B
  int*     csr    = (int*)(w + 51931136);         // 3,200,000 B
  double*  st     = (double*)(w + 55131136);      // 16 B
  float*   scal   = (float*)(w + 55131152);       // 8 B
  int*     presc  = (int*)(w + 55131200);         // 200,000 B
  int*     spart  = (int*)(w + 55331200);         // 256 B
  int*     sboff  = (int*)(w + 55331456);         // 256 B
  __half2* xh     = (__half2*)(w + 55331712);     // 12,800,000 B (reused as act-half)

  hipMemsetAsync(deg, 0, NN * sizeof(int), stream);
  hipMemsetAsync(st, 0, 2 * sizeof(double), stream);

  k_transpose<<<64, 256, 0, stream>>>(W1, Wt1);
  k_transpose<<<64, 256, 0, stream>>>(W2, Wt2);
  k_hist<<<(NE + 255) / 256, 256, 0, stream>>>(dstI, deg);
  k_scan_p1<<<NBLK_SCAN, 256, 0, stream>>>(deg, spart, presc);
  k_scan_p2<<<1, 64, 0, stream>>>(spart, sboff);
  k_scan_p3<<<(NN + 255) / 256, 256, 0, stream>>>(presc, sboff, rowst, cursor);
  k_fill<<<(NE + 255) / 256, 256, 0, stream>>>(srcI, dstI, cursor, csr);
  k_tohalf<<<(NN * C / 4 + 255) / 256, 256, 0, stream>>>(x, xh);

  // layer 1
  k_agg_h<<<(NN + 3) / 4, 256, 0, stream>>>(xh, x, rowst, csr, eps1, A);
  k_gemm<<<(NN + GN - 1) / GN, 256, 0, stream>>>(A, Wt1, b1, B);

  // graph layernorm + prelu (also emits fp16 copy into xh)
  k_stats<<<1024, 256, 0, stream>>>(B, st);
  k_final<<<1, 1, 0, stream>>>(st, scal);
  k_act<<<(NN * C / 4 + 255) / 256, 256, 0, stream>>>(B, scal, lnw, lnb, pa, A, xh);

  // layer 2
  k_agg_h<<<(NN + 3) / 4, 256, 0, stream>>>(xh, A, rowst, csr, eps2, B);
  k_gemm<<<(NN + GN - 1) / GN, 256, 0, stream>>>(B, Wt2, b2, out);
}

// Round 5
// 352.882 us; speedup vs baseline: 1.4535x; 1.0694x over previous
//
#include <hip/hip_runtime.h>
#include <hip/hip_fp16.h>
#include <math.h>

#define NN 50000
#define NE 800000
#define C  128
#define SCAN_ELEM 1024 // elements per scan block
#define NBLK_SCAN ((NN + SCAN_ELEM - 1) / SCAN_ELEM)   // 49

typedef _Float16 f16x8 __attribute__((ext_vector_type(8)));
typedef float f32x4 __attribute__((ext_vector_type(4)));

// ---------- W fp32 -> fp16 (row-major [o][c] kept) ----------
__global__ void k_wh(const float* __restrict__ W, _Float16* __restrict__ Wh) {
  int i = blockIdx.x * 256 + threadIdx.x;
  if (i < C * C) Wh[i] = (_Float16)W[i];
}

// ---------- histogram: 4 edges/thread ----------
__global__ __launch_bounds__(256) void k_hist4(const int* __restrict__ dst,
                                               int* __restrict__ deg) {
  int i = blockIdx.x * 256 + threadIdx.x;
  if (i < NE / 4) {
    int4 d = ((const int4*)dst)[i];
    atomicAdd(&deg[d.x], 1); atomicAdd(&deg[d.y], 1);
    atomicAdd(&deg[d.z], 1); atomicAdd(&deg[d.w], 1);
  }
}

// ---------- device-wide exclusive scan, 3 phases ----------
__global__ __launch_bounds__(256) void k_scan_p1(const int* __restrict__ deg,
                                                 int* __restrict__ partial,
                                                 int* __restrict__ prescan) {
  int t = threadIdx.x;
  int base = blockIdx.x * SCAN_ELEM;
  int idx = base + t * 4;
  int4 v = make_int4(0, 0, 0, 0);
  if (idx + 3 < NN) {
    v = *(const int4*)(deg + idx);
  } else {
    if (idx + 0 < NN) v.x = deg[idx + 0];
    if (idx + 1 < NN) v.y = deg[idx + 1];
    if (idx + 2 < NN) v.z = deg[idx + 2];
    if (idx + 3 < NN) v.w = deg[idx + 3];
  }
  int s0 = v.x, s1 = s0 + v.y, s2 = s1 + v.z, s3 = s2 + v.w;
  int tsum = s3;
  int lane = t & 63;
  int incl = tsum;
  #pragma unroll
  for (int off = 1; off < 64; off <<= 1) {
    int u = __shfl_up(incl, off, 64);
    if (lane >= off) incl += u;
  }
  __shared__ int wsum[4];
  int wid = t >> 6;
  if (lane == 63) wsum[wid] = incl;
  __syncthreads();
  int woff = 0;
  for (int wI = 0; wI < wid; ++wI) woff += wsum[wI];
  int texcl = woff + incl - tsum;
  if (idx + 0 < NN) prescan[idx + 0] = texcl;
  if (idx + 1 < NN) prescan[idx + 1] = texcl + s0;
  if (idx + 2 < NN) prescan[idx + 2] = texcl + s1;
  if (idx + 3 < NN) prescan[idx + 3] = texcl + s2;
  if (t == 255) partial[blockIdx.x] = woff + incl;
}

__global__ __launch_bounds__(64) void k_scan_p2(const int* __restrict__ partial,
                                                int* __restrict__ blkoff) {
  int t = threadIdx.x;
  int v = (t < NBLK_SCAN) ? partial[t] : 0;
  int incl = v;
  #pragma unroll
  for (int off = 1; off < 64; off <<= 1) {
    int u = __shfl_up(incl, off, 64);
    if (t >= off) incl += u;
  }
  if (t < NBLK_SCAN) blkoff[t] = incl - v;
}

__global__ __launch_bounds__(256) void k_scan_p3(const int* __restrict__ prescan,
                                                 const int* __restrict__ blkoff,
                                                 int* __restrict__ rowstart,
                                                 int* __restrict__ cursor) {
  int i = blockIdx.x * 256 + threadIdx.x;
  if (i < NN) {
    int v = prescan[i] + blkoff[i >> 10];
    rowstart[i] = v;
    cursor[i] = v;
  }
  if (i == 0) rowstart[NN] = NE;
}

// ---------- CSR fill: 4 edges/thread ----------
__global__ __launch_bounds__(256) void k_fill4(const int* __restrict__ src,
                       const int* __restrict__ dst,
                       int* __restrict__ cursor, int* __restrict__ csr) {
  int i = blockIdx.x * 256 + threadIdx.x;
  if (i < NE / 4) {
    int4 s = ((const int4*)src)[i];
    int4 d = ((const int4*)dst)[i];
    int p0 = atomicAdd(&cursor[d.x], 1);
    int p1 = atomicAdd(&cursor[d.y], 1);
    int p2 = atomicAdd(&cursor[d.z], 1);
    int p3 = atomicAdd(&cursor[d.w], 1);
    csr[p0] = s.x; csr[p1] = s.y; csr[p2] = s.z; csr[p3] = s.w;
  }
}

// ---------- fp32 -> fp16 row copy ----------
__global__ __launch_bounds__(256) void k_tohalf(const float* __restrict__ in,
                                                __half2* __restrict__ o) {
  int i = blockIdx.x * 256 + threadIdx.x;   // float4 index
  if (i < NN * C / 4) {
    float4 v = ((const float4*)in)[i];
    o[2 * i]     = __floats2half2_rn(v.x, v.y);
    o[2 * i + 1] = __floats2half2_rn(v.z, v.w);
  }
}

// ---------- aggregation: one wave per node, fp16 gather+self, fp16 out ----------
__global__ __launch_bounds__(256) void k_agg_h(const __half2* __restrict__ xh2,
                       const int* __restrict__ rs, const int* __restrict__ csr,
                       const float* __restrict__ eps_p, __half2* __restrict__ preh2) {
  int wid = threadIdx.x >> 6;
  int lane = threadIdx.x & 63;
  int n = blockIdx.x * 4 + wid;
  if (n >= NN) return;
  int s0 = rs[n], s1 = rs[n + 1];
  float a0 = -INFINITY, a1 = -INFINITY;
  float b0 = -INFINITY, b1 = -INFINITY;
  float c0 = -INFINITY, c1 = -INFINITY;
  float d0 = -INFINITY, d1 = -INFINITY;
  int j = s0;
  for (; j + 3 < s1; j += 4) {
    int e0 = csr[j], e1_ = csr[j + 1], e2 = csr[j + 2], e3 = csr[j + 3];
    __half2 v0 = xh2[(size_t)e0 * 64 + lane];
    __half2 v1 = xh2[(size_t)e1_ * 64 + lane];
    __half2 v2 = xh2[(size_t)e2 * 64 + lane];
    __half2 v3 = xh2[(size_t)e3 * 64 + lane];
    a0 = fmaxf(a0, __low2float(v0)); a1 = fmaxf(a1, __high2float(v0));
    b0 = fmaxf(b0, __low2float(v1)); b1 = fmaxf(b1, __high2float(v1));
    c0 = fmaxf(c0, __low2float(v2)); c1 = fmaxf(c1, __high2float(v2));
    d0 = fmaxf(d0, __low2float(v3)); d1 = fmaxf(d1, __high2float(v3));
  }
  for (; j < s1; ++j) {
    int e0 = csr[j];
    __half2 v0 = xh2[(size_t)e0 * 64 + lane];
    a0 = fmaxf(a0, __low2float(v0)); a1 = fmaxf(a1, __high2float(v0));
  }
  float m0 = fmaxf(fmaxf(a0, b0), fmaxf(c0, d0));
  float m1 = fmaxf(fmaxf(a1, b1), fmaxf(c1, d1));
  if (s1 == s0) { m0 = 0.f; m1 = 0.f; }   // empty segment -> 0 (PyG fill)
  float e1v = 1.0f + eps_p[0];
  __half2 xs = xh2[(size_t)n * 64 + lane];
  float ox = fmaf(e1v, __low2float(xs), m0);
  float oy = fmaf(e1v, __high2float(xs), m1);
  preh2[(size_t)n * 64 + lane] = __floats2half2_rn(ox, oy);
}

// ---------- MFMA GEMM: out[n][o] = sum_c Ah[n][c] * Wh[o][c] + bias[o] ----------
// 1 wave = 16 nodes x 128 out; A-frag: lane holds Ah[nt*16 + (l&15)][kq*8..+7 + kk*32]
// B-frag: lane holds Wh[ot*16 + (l&15)][same k slice]; D: col=lane&15, row=(lane>>4)*4+j
__global__ __launch_bounds__(256) void k_gemm_f16(const _Float16* __restrict__ Ah,
                       const _Float16* __restrict__ Wh, const float* __restrict__ bias,
                       float* __restrict__ out) {
  int wid = threadIdx.x >> 6, lane = threadIdx.x & 63;
  int nt = blockIdx.x * 4 + wid;          // 16-node tile id
  if (nt >= NN / 16) return;              // 3125 tiles exactly
  int r = lane & 15;
  int kq = lane >> 4;
  const _Float16* arow = Ah + ((size_t)nt * 16 + r) * C + kq * 8;

  f32x4 acc[8];
  #pragma unroll
  for (int ot = 0; ot < 8; ++ot) {
    float bv = bias[ot * 16 + r];
    f32x4 z = {bv, bv, bv, bv};
    acc[ot] = z;
  }

  #pragma unroll
  for (int kk = 0; kk < 4; ++kk) {
    f16x8 a = *(const f16x8*)(arow + kk * 32);
    #pragma unroll
    for (int ot = 0; ot < 8; ++ot) {
      f16x8 b = *(const f16x8*)(Wh + ((size_t)ot * 16 + r) * C + kk * 32 + kq * 8);
      acc[ot] = __builtin_amdgcn_mfma_f32_16x16x32_f16(a, b, acc[ot], 0, 0, 0);
    }
  }

  size_t nbase = (size_t)nt * 16;
  #pragma unroll
  for (int ot = 0; ot < 8; ++ot) {
    #pragma unroll
    for (int j = 0; j < 4; ++j) {
      out[(nbase + kq * 4 + j) * C + ot * 16 + r] = acc[ot][j];
    }
  }
}

// ---------- global LayerNorm stats (sum, sumsq over all N*C) ----------
__global__ __launch_bounds__(256) void k_stats(const float* __restrict__ h,
                                               double* __restrict__ st) {
  const int NV = NN * C / 4;
  int stride = gridDim.x * blockDim.x;
  double s = 0.0, ss = 0.0;
  for (int i = blockIdx.x * blockDim.x + threadIdx.x; i < NV; i += stride) {
    float4 v = ((const float4*)h)[i];
    s  += (double)v.x + (double)v.y + (double)v.z + (double)v.w;
    ss += (double)v.x * v.x + (double)v.y * v.y + (double)v.z * v.z + (double)v.w * v.w;
  }
  for (int off = 32; off > 0; off >>= 1) {
    s  += __shfl_down(s, off, 64);
    ss += __shfl_down(ss, off, 64);
  }
  __shared__ double sd[4], ssd[4];
  int wid = threadIdx.x >> 6, lane = threadIdx.x & 63;
  if (lane == 0) { sd[wid] = s; ssd[wid] = ss; }
  __syncthreads();
  if (threadIdx.x == 0) {
    double ts = sd[0] + sd[1] + sd[2] + sd[3];
    double tss = ssd[0] + ssd[1] + ssd[2] + ssd[3];
    atomicAdd(&st[0], ts);
    atomicAdd(&st[1], tss);
  }
}

__global__ void k_final(const double* __restrict__ st, float* __restrict__ scal) {
  double M = (double)NN * C;
  double mean = st[0] / M;
  double var = st[1] / M - mean * mean;
  if (var < 0.0) var = 0.0;
  double stdv = sqrt(var);
  scal[0] = (float)mean;
  scal[1] = (float)(1.0 / (stdv + 1e-5));
}

// ---------- LN apply + PReLU -> fp16 only (layer2 reads fp16 for gather+self) ----------
__global__ __launch_bounds__(256) void k_act(const float* __restrict__ h,
                       const float* __restrict__ scal,
                       const float* __restrict__ lw, const float* __restrict__ lb,
                       const float* __restrict__ a_p, __half2* __restrict__ outh) {
  int i = blockIdx.x * 256 + threadIdx.x;   // float4 index, total NN*C/4
  if (i >= NN * C / 4) return;
  float mean = scal[0], inv = scal[1], a = a_p[0];
  float4 v = ((const float4*)h)[i];
  int c4 = i & 31;
  float4 w = ((const float4*)lw)[c4];
  float4 b = ((const float4*)lb)[c4];
  float r[4];
  r[0] = (v.x - mean) * inv * w.x + b.x;
  r[1] = (v.y - mean) * inv * w.y + b.y;
  r[2] = (v.z - mean) * inv * w.z + b.z;
  r[3] = (v.w - mean) * inv * w.w + b.w;
  #pragma unroll
  for (int k = 0; k < 4; ++k) r[k] = (r[k] >= 0.f) ? r[k] : a * r[k];
  outh[2 * i]     = __floats2half2_rn(r[0], r[1]);
  outh[2 * i + 1] = __floats2half2_rn(r[2], r[3]);
}

extern "C" void kernel_launch(void* const* d_in, const int* in_sizes, int n_in,
                              void* d_out, int out_size, void* d_ws, size_t ws_size,
                              hipStream_t stream) {
  const float* x    = (const float*)d_in[0];
  const int*   ei   = (const int*)d_in[1];
  const float* eps1 = (const float*)d_in[2];
  const float* W1   = (const float*)d_in[3];
  const float* b1   = (const float*)d_in[4];
  const float* lnw  = (const float*)d_in[5];
  const float* lnb  = (const float*)d_in[6];
  const float* pa   = (const float*)d_in[7];
  const float* eps2 = (const float*)d_in[8];
  const float* W2   = (const float*)d_in[9];
  const float* b2   = (const float*)d_in[10];
  float* out = (float*)d_out;
  const int* srcI = ei;         // edge_index[0]
  const int* dstI = ei + NE;    // edge_index[1]

  char* w = (char*)d_ws;
  float*    B      = (float*)(w);                  // 25,600,000 B (gemm1 out)
  __half2*  preh   = (__half2*)(w + 25600000);     // 12,800,000 B (agg out / gemm A)
  __half2*  xh     = (__half2*)(w + 38400000);     // 12,800,000 B (gather table)
  _Float16* Wh1    = (_Float16*)(w + 51200000);    // 32,768 B
  _Float16* Wh2    = (_Float16*)(w + 51232768);    // 32,768 B
  int*      deg    = (int*)(w + 51265536);         // 200,000 B
  int*      rowst  = (int*)(w + 51465536);         // 200,064 B (N+1 ints)
  int*      cursor = (int*)(w + 51665600);         // 200,000 B
  int*      csr    = (int*)(w + 51865600);         // 3,200,000 B
  double*   st     = (double*)(w + 55065600);      // 16 B
  float*    scal   = (float*)(w + 55065616);       // 8 B (+pad)
  int*      presc  = (int*)(w + 55065632);         // 200,000 B
  int*      spart  = (int*)(w + 55265632);         // 256 B
  int*      sboff  = (int*)(w + 55265888);         // 256 B

  hipMemsetAsync(deg, 0, NN * sizeof(int), stream);
  hipMemsetAsync(st, 0, 2 * sizeof(double), stream);

  k_wh<<<64, 256, 0, stream>>>(W1, Wh1);
  k_wh<<<64, 256, 0, stream>>>(W2, Wh2);
  k_hist4<<<(NE / 4 + 255) / 256, 256, 0, stream>>>(dstI, deg);
  k_scan_p1<<<NBLK_SCAN, 256, 0, stream>>>(deg, spart, presc);
  k_scan_p2<<<1, 64, 0, stream>>>(spart, sboff);
  k_scan_p3<<<(NN + 255) / 256, 256, 0, stream>>>(presc, sboff, rowst, cursor);
  k_fill4<<<(NE / 4 + 255) / 256, 256, 0, stream>>>(srcI, dstI, cursor, csr);
  k_tohalf<<<(NN * C / 4 + 255) / 256, 256, 0, stream>>>(x, xh);

  // layer 1
  k_agg_h<<<(NN + 3) / 4, 256, 0, stream>>>(xh, rowst, csr, eps1, preh);
  k_gemm_f16<<<(NN / 16 + 3) / 4, 256, 0, stream>>>((const _Float16*)preh, Wh1, b1, B);

  // graph layernorm + prelu (fp16 out into xh for layer2)
  k_stats<<<1024, 256, 0, stream>>>(B, st);
  k_final<<<1, 1, 0, stream>>>(st, scal);
  k_act<<<(NN * C / 4 + 255) / 256, 256, 0, stream>>>(B, scal, lnw, lnb, pa, xh);

  // layer 2
  k_agg_h<<<(NN + 3) / 4, 256, 0, stream>>>(xh, rowst, csr, eps2, preh);
  k_gemm_f16<<<(NN / 16 + 3) / 4, 256, 0, stream>>>((const _Float16*)preh, Wh2, b2, out);
}

// Round 6
// 285.094 us; speedup vs baseline: 1.7991x; 1.2378x over previous
//
#include <hip/hip_runtime.h>
#include <hip/hip_fp16.h>
#include <math.h>

#define NN 50000
#define NE 800000
#define C  128
#define BKT 128                                   // node ids per bucket
#define NBUK ((NN + BKT - 1) / BKT)               // 391
#define ECHUNK 2048                               // edges per partition chunk
#define NEBLK ((NE + ECHUNK - 1) / ECHUNK)        // 391

typedef _Float16 f16x8 __attribute__((ext_vector_type(8)));
typedef float f32x4 __attribute__((ext_vector_type(4)));

// ---------- W fp32 -> fp16 (row-major [o][c] kept) ----------
__global__ void k_wh(const float* __restrict__ W, _Float16* __restrict__ Wh) {
  int i = blockIdx.x * 256 + threadIdx.x;
  if (i < C * C) Wh[i] = (_Float16)W[i];
}

// ---------- phase 1: per-chunk bucket histogram (LDS only) ----------
__global__ __launch_bounds__(256) void k_bh(const int* __restrict__ dst,
                                            int* __restrict__ bh) {
  __shared__ int h[NBUK];
  int t = threadIdx.x;
  for (int i = t; i < NBUK; i += 256) h[i] = 0;
  __syncthreads();
  int base = blockIdx.x * ECHUNK;
  int end = base + ECHUNK; if (end > NE) end = NE;
  for (int e = base + t; e < end; e += 256) atomicAdd(&h[dst[e] >> 7], 1);
  __syncthreads();
  for (int i = t; i < NBUK; i += 256) bh[i * NEBLK + blockIdx.x] = h[i];
}

// ---------- phase 2: per-bucket exclusive scan over chunk counts ----------
__global__ __launch_bounds__(256) void k_bscan(int* __restrict__ bh,
                                               int* __restrict__ btot) {
  int b = blockIdx.x, t = threadIdx.x;
  int lane = t & 63, wid = t >> 6;
  __shared__ int wsum[4];
  int carry = 0;   // per-thread, identically recomputed
  for (int base = 0; base < NEBLK; base += 256) {
    int i = base + t;
    int v = (i < NEBLK) ? bh[b * NEBLK + i] : 0;
    int incl = v;
    #pragma unroll
    for (int off = 1; off < 64; off <<= 1) {
      int u = __shfl_up(incl, off, 64);
      if (lane >= off) incl += u;
    }
    if (lane == 63) wsum[wid] = incl;
    __syncthreads();
    int woff = 0;
    #pragma unroll
    for (int wI = 0; wI < 4; ++wI) if (wI < wid) woff += wsum[wI];
    if (i < NEBLK) bh[b * NEBLK + i] = carry + woff + incl - v;
    int total = wsum[0] + wsum[1] + wsum[2] + wsum[3];
    __syncthreads();
    carry += total;
  }
  if (t == 0) btot[b] = carry;
}

// ---------- phase 3: scan bucket totals -> bucket bases ----------
__global__ __launch_bounds__(256) void k_bbase(const int* __restrict__ btot,
                                               int* __restrict__ bbase,
                                               int* __restrict__ rowstart) {
  int t = threadIdx.x;
  int lane = t & 63, wid = t >> 6;
  __shared__ int wsum[4];
  int carry = 0;
  for (int base = 0; base < NBUK; base += 256) {
    int i = base + t;
    int v = (i < NBUK) ? btot[i] : 0;
    int incl = v;
    #pragma unroll
    for (int off = 1; off < 64; off <<= 1) {
      int u = __shfl_up(incl, off, 64);
      if (lane >= off) incl += u;
    }
    if (lane == 63) wsum[wid] = incl;
    __syncthreads();
    int woff = 0;
    #pragma unroll
    for (int wI = 0; wI < 4; ++wI) if (wI < wid) woff += wsum[wI];
    if (i < NBUK) bbase[i] = carry + woff + incl - v;
    int total = wsum[0] + wsum[1] + wsum[2] + wsum[3];
    __syncthreads();
    carry += total;
  }
  if (t == 0) rowstart[NN] = NE;
}

// ---------- phase 4: scatter edges into bucket-major binned array ----------
__global__ __launch_bounds__(256) void k_bscatter(const int* __restrict__ src,
                       const int* __restrict__ dst,
                       const int* __restrict__ bh, const int* __restrict__ bbase,
                       int2* __restrict__ binned) {
  __shared__ int cur[NBUK];
  int t = threadIdx.x, blk = blockIdx.x;
  for (int i = t; i < NBUK; i += 256) cur[i] = bbase[i] + bh[i * NEBLK + blk];
  __syncthreads();
  int base = blk * ECHUNK;
  int end = base + ECHUNK; if (end > NE) end = NE;
  for (int e = base + t; e < end; e += 256) {
    int d = dst[e];
    int pos = atomicAdd(&cur[d >> 7], 1);
    binned[pos] = make_int2(src[e], d);
  }
}

// ---------- phase 5: per-bucket CSR fill + rowstart (LDS hist+scan) ----------
__global__ __launch_bounds__(256) void k_bfill(const int2* __restrict__ binned,
                       const int* __restrict__ bbase, const int* __restrict__ btot,
                       int* __restrict__ rowstart, int* __restrict__ csr) {
  int b = blockIdx.x, t = threadIdx.x;
  __shared__ int hist[BKT];
  __shared__ int cur[BKT];
  __shared__ int wsum[4];
  int s0 = bbase[b];
  int cnt = btot[b];
  if (t < BKT) hist[t] = 0;
  __syncthreads();
  for (int j = t; j < cnt; j += 256) atomicAdd(&hist[binned[s0 + j].y & (BKT - 1)], 1);
  __syncthreads();
  int v = (t < BKT) ? hist[t] : 0;
  int lane = t & 63, wid = t >> 6;
  int incl = v;
  #pragma unroll
  for (int off = 1; off < 64; off <<= 1) {
    int u = __shfl_up(incl, off, 64);
    if (lane >= off) incl += u;
  }
  if (lane == 63) wsum[wid] = incl;
  __syncthreads();
  int woff = 0;
  #pragma unroll
  for (int wI = 0; wI < 4; ++wI) if (wI < wid) woff += wsum[wI];
  int excl = woff + incl - v;
  if (t < BKT) {
    cur[t] = excl;
    int node = b * BKT + t;
    if (node < NN) rowstart[node] = s0 + excl;
  }
  __syncthreads();
  for (int j = t; j < cnt; j += 256) {
    int2 sd = binned[s0 + j];
    int p = atomicAdd(&cur[sd.y & (BKT - 1)], 1);
    csr[s0 + p] = sd.x;
  }
}

// ---------- fp32 -> fp16 row copy ----------
__global__ __launch_bounds__(256) void k_tohalf(const float* __restrict__ in,
                                                __half2* __restrict__ o) {
  int i = blockIdx.x * 256 + threadIdx.x;   // float4 index
  if (i < NN * C / 4) {
    float4 v = ((const float4*)in)[i];
    o[2 * i]     = __floats2half2_rn(v.x, v.y);
    o[2 * i + 1] = __floats2half2_rn(v.z, v.w);
  }
}

// ---------- aggregation: one wave per node, fp16 gather+self, fp16 out ----------
__global__ __launch_bounds__(256) void k_agg_h(const __half2* __restrict__ xh2,
                       const int* __restrict__ rs, const int* __restrict__ csr,
                       const float* __restrict__ eps_p, __half2* __restrict__ preh2) {
  int wid = threadIdx.x >> 6;
  int lane = threadIdx.x & 63;
  int n = blockIdx.x * 4 + wid;
  if (n >= NN) return;
  int s0 = rs[n], s1 = rs[n + 1];
  float a0 = -INFINITY, a1 = -INFINITY;
  float b0 = -INFINITY, b1 = -INFINITY;
  float c0 = -INFINITY, c1 = -INFINITY;
  float d0 = -INFINITY, d1 = -INFINITY;
  int j = s0;
  for (; j + 3 < s1; j += 4) {
    int e0 = csr[j], e1_ = csr[j + 1], e2 = csr[j + 2], e3 = csr[j + 3];
    __half2 v0 = xh2[(size_t)e0 * 64 + lane];
    __half2 v1 = xh2[(size_t)e1_ * 64 + lane];
    __half2 v2 = xh2[(size_t)e2 * 64 + lane];
    __half2 v3 = xh2[(size_t)e3 * 64 + lane];
    a0 = fmaxf(a0, __low2float(v0)); a1 = fmaxf(a1, __high2float(v0));
    b0 = fmaxf(b0, __low2float(v1)); b1 = fmaxf(b1, __high2float(v1));
    c0 = fmaxf(c0, __low2float(v2)); c1 = fmaxf(c1, __high2float(v2));
    d0 = fmaxf(d0, __low2float(v3)); d1 = fmaxf(d1, __high2float(v3));
  }
  for (; j < s1; ++j) {
    int e0 = csr[j];
    __half2 v0 = xh2[(size_t)e0 * 64 + lane];
    a0 = fmaxf(a0, __low2float(v0)); a1 = fmaxf(a1, __high2float(v0));
  }
  float m0 = fmaxf(fmaxf(a0, b0), fmaxf(c0, d0));
  float m1 = fmaxf(fmaxf(a1, b1), fmaxf(c1, d1));
  if (s1 == s0) { m0 = 0.f; m1 = 0.f; }   // empty segment -> 0 (PyG fill)
  float e1v = 1.0f + eps_p[0];
  __half2 xs = xh2[(size_t)n * 64 + lane];
  float ox = fmaf(e1v, __low2float(xs), m0);
  float oy = fmaf(e1v, __high2float(xs), m1);
  preh2[(size_t)n * 64 + lane] = __floats2half2_rn(ox, oy);
}

// ---------- MFMA GEMM: out[n][o] = sum_c Ah[n][c] * Wh[o][c] + bias[o] ----------
__global__ __launch_bounds__(256) void k_gemm_f16(const _Float16* __restrict__ Ah,
                       const _Float16* __restrict__ Wh, const float* __restrict__ bias,
                       float* __restrict__ out) {
  int wid = threadIdx.x >> 6, lane = threadIdx.x & 63;
  int nt = blockIdx.x * 4 + wid;          // 16-node tile id
  if (nt >= NN / 16) return;              // 3125 tiles exactly
  int r = lane & 15;
  int kq = lane >> 4;
  const _Float16* arow = Ah + ((size_t)nt * 16 + r) * C + kq * 8;

  f32x4 acc[8];
  #pragma unroll
  for (int ot = 0; ot < 8; ++ot) {
    float bv = bias[ot * 16 + r];
    f32x4 z = {bv, bv, bv, bv};
    acc[ot] = z;
  }

  #pragma unroll
  for (int kk = 0; kk < 4; ++kk) {
    f16x8 a = *(const f16x8*)(arow + kk * 32);
    #pragma unroll
    for (int ot = 0; ot < 8; ++ot) {
      f16x8 b = *(const f16x8*)(Wh + ((size_t)ot * 16 + r) * C + kk * 32 + kq * 8);
      acc[ot] = __builtin_amdgcn_mfma_f32_16x16x32_f16(a, b, acc[ot], 0, 0, 0);
    }
  }

  size_t nbase = (size_t)nt * 16;
  #pragma unroll
  for (int ot = 0; ot < 8; ++ot) {
    #pragma unroll
    for (int j = 0; j < 4; ++j) {
      out[(nbase + kq * 4 + j) * C + ot * 16 + r] = acc[ot][j];
    }
  }
}

// ---------- global LayerNorm stats (sum, sumsq over all N*C) ----------
__global__ __launch_bounds__(256) void k_stats(const float* __restrict__ h,
                                               double* __restrict__ st) {
  const int NV = NN * C / 4;
  int stride = gridDim.x * blockDim.x;
  double s = 0.0, ss = 0.0;
  for (int i = blockIdx.x * blockDim.x + threadIdx.x; i < NV; i += stride) {
    float4 v = ((const float4*)h)[i];
    s  += (double)v.x + (double)v.y + (double)v.z + (double)v.w;
    ss += (double)v.x * v.x + (double)v.y * v.y + (double)v.z * v.z + (double)v.w * v.w;
  }
  for (int off = 32; off > 0; off >>= 1) {
    s  += __shfl_down(s, off, 64);
    ss += __shfl_down(ss, off, 64);
  }
  __shared__ double sd[4], ssd[4];
  int wid = threadIdx.x >> 6, lane = threadIdx.x & 63;
  if (lane == 0) { sd[wid] = s; ssd[wid] = ss; }
  __syncthreads();
  if (threadIdx.x == 0) {
    double ts = sd[0] + sd[1] + sd[2] + sd[3];
    double tss = ssd[0] + ssd[1] + ssd[2] + ssd[3];
    atomicAdd(&st[0], ts);
    atomicAdd(&st[1], tss);
  }
}

__global__ void k_final(const double* __restrict__ st, float* __restrict__ scal) {
  double M = (double)NN * C;
  double mean = st[0] / M;
  double var = st[1] / M - mean * mean;
  if (var < 0.0) var = 0.0;
  double stdv = sqrt(var);
  scal[0] = (float)mean;
  scal[1] = (float)(1.0 / (stdv + 1e-5));
}

// ---------- LN apply + PReLU -> fp16 only ----------
__global__ __launch_bounds__(256) void k_act(const float* __restrict__ h,
                       const float* __restrict__ scal,
                       const float* __restrict__ lw, const float* __restrict__ lb,
                       const float* __restrict__ a_p, __half2* __restrict__ outh) {
  int i = blockIdx.x * 256 + threadIdx.x;   // float4 index, total NN*C/4
  if (i >= NN * C / 4) return;
  float mean = scal[0], inv = scal[1], a = a_p[0];
  float4 v = ((const float4*)h)[i];
  int c4 = i & 31;
  float4 w = ((const float4*)lw)[c4];
  float4 b = ((const float4*)lb)[c4];
  float r[4];
  r[0] = (v.x - mean) * inv * w.x + b.x;
  r[1] = (v.y - mean) * inv * w.y + b.y;
  r[2] = (v.z - mean) * inv * w.z + b.z;
  r[3] = (v.w - mean) * inv * w.w + b.w;
  #pragma unroll
  for (int k = 0; k < 4; ++k) r[k] = (r[k] >= 0.f) ? r[k] : a * r[k];
  outh[2 * i]     = __floats2half2_rn(r[0], r[1]);
  outh[2 * i + 1] = __floats2half2_rn(r[2], r[3]);
}

extern "C" void kernel_launch(void* const* d_in, const int* in_sizes, int n_in,
                              void* d_out, int out_size, void* d_ws, size_t ws_size,
                              hipStream_t stream) {
  const float* x    = (const float*)d_in[0];
  const int*   ei   = (const int*)d_in[1];
  const float* eps1 = (const float*)d_in[2];
  const float* W1   = (const float*)d_in[3];
  const float* b1   = (const float*)d_in[4];
  const float* lnw  = (const float*)d_in[5];
  const float* lnb  = (const float*)d_in[6];
  const float* pa   = (const float*)d_in[7];
  const float* eps2 = (const float*)d_in[8];
  const float* W2   = (const float*)d_in[9];
  const float* b2   = (const float*)d_in[10];
  float* out = (float*)d_out;
  const int* srcI = ei;         // edge_index[0]
  const int* dstI = ei + NE;    // edge_index[1]

  char* w = (char*)d_ws;
  float*    B      = (float*)(w);                  // 25,600,000 B (gemm1 out)
  __half2*  preh   = (__half2*)(w + 25600000);     // 12,800,000 B (agg out / gemm A)
  __half2*  xh     = (__half2*)(w + 38400000);     // 12,800,000 B (gather table)
  _Float16* Wh1    = (_Float16*)(w + 51200000);    // 32,768 B
  _Float16* Wh2    = (_Float16*)(w + 51232768);    // 32,768 B
  int*      rowst  = (int*)(w + 51265536);         // 200,064 B (N+1 ints)
  int*      csr    = (int*)(w + 51465600);         // 3,200,000 B
  int2*     binned = (int2*)(w + 54665600);        // 6,400,000 B
  int*      bh     = (int*)(w + 61065600);         // 611,584 B (NBUK*NEBLK ints)
  int*      btot   = (int*)(w + 61677184);         // 1,664 B
  int*      bbase  = (int*)(w + 61678848);         // 1,664 B
  double*   st     = (double*)(w + 61680512);      // 16 B
  float*    scal   = (float*)(w + 61680528);       // 8 B

  hipMemsetAsync(st, 0, 2 * sizeof(double), stream);

  k_wh<<<64, 256, 0, stream>>>(W1, Wh1);
  k_wh<<<64, 256, 0, stream>>>(W2, Wh2);

  // CSR build via bucketed multisplit (no global-random scatter)
  k_bh<<<NEBLK, 256, 0, stream>>>(dstI, bh);
  k_bscan<<<NBUK, 256, 0, stream>>>(bh, btot);
  k_bbase<<<1, 256, 0, stream>>>(btot, bbase, rowst);
  k_bscatter<<<NEBLK, 256, 0, stream>>>(srcI, dstI, bh, bbase, binned);
  k_bfill<<<NBUK, 256, 0, stream>>>(binned, bbase, btot, rowst, csr);

  k_tohalf<<<(NN * C / 4 + 255) / 256, 256, 0, stream>>>(x, xh);

  // layer 1
  k_agg_h<<<(NN + 3) / 4, 256, 0, stream>>>(xh, rowst, csr, eps1, preh);
  k_gemm_f16<<<(NN / 16 + 3) / 4, 256, 0, stream>>>((const _Float16*)preh, Wh1, b1, B);

  // graph layernorm + prelu (fp16 out into xh for layer2)
  k_stats<<<1024, 256, 0, stream>>>(B, st);
  k_final<<<1, 1, 0, stream>>>(st, scal);
  k_act<<<(NN * C / 4 + 255) / 256, 256, 0, stream>>>(B, scal, lnw, lnb, pa, xh);

  // layer 2
  k_agg_h<<<(NN + 3) / 4, 256, 0, stream>>>(xh, rowst, csr, eps2, preh);
  k_gemm_f16<<<(NN / 16 + 3) / 4, 256, 0, stream>>>((const _Float16*)preh, Wh2, b2, out);
}